// Round 8
// baseline (219.405 us; speedup 1.0000x reference)
//
#include <hip/hip_runtime.h>
#include <hip/hip_bf16.h>
#include <hip/hip_fp16.h>
#include <math.h>

static constexpr int D  = 64;     // input dim
static constexpr int F1 = 1024;   // H1*C1
static constexpr int NTOT = 3072; // 3 fused GEMM outputs
static constexpr int EW  = 64;    // ELL width (max deg; Poisson(8)+1 graph)

typedef _Float16 f16x8 __attribute__((ext_vector_type(8)));  // MFMA A/B frag
typedef _Float16 h2    __attribute__((ext_vector_type(2)));  // packed pair
typedef float    f32x4 __attribute__((ext_vector_type(4)));
typedef unsigned int u32x4 __attribute__((ext_vector_type(4)));

__device__ __forceinline__ float lrelu(float x) { return x > 0.f ? x : 0.2f * x; }

// dot of two f16 pairs, f32 accumulate (v_dot2_f32_f16 when available)
__device__ __forceinline__ float dot2f(h2 a, h2 b, float c) {
#if __has_builtin(__builtin_amdgcn_fdot2)
    return __builtin_amdgcn_fdot2(a, b, c, false);
#else
    return c + (float)a[0] * (float)b[0] + (float)a[1] * (float)b[1];
#endif
}

// 16-lane sum via DPP row ops (VALU pipe): xor1=0xB1, xor2=0x4E,
// xor4=row_half_mirror(0x141), xor8=row_mirror(0x140).
__device__ __forceinline__ float red16(float p) {
    int v = __builtin_bit_cast(int, p);
    p += __builtin_bit_cast(float, __builtin_amdgcn_mov_dpp(v, 0xB1, 0xF, 0xF, true));
    v = __builtin_bit_cast(int, p);
    p += __builtin_bit_cast(float, __builtin_amdgcn_mov_dpp(v, 0x4E, 0xF, 0xF, true));
    v = __builtin_bit_cast(int, p);
    p += __builtin_bit_cast(float, __builtin_amdgcn_mov_dpp(v, 0x141, 0xF, 0xF, true));
    v = __builtin_bit_cast(int, p);
    p += __builtin_bit_cast(float, __builtin_amdgcn_mov_dpp(v, 0x140, 0xF, 0xF, true));
    return p;
}

union U4H { uint4 u; h2 h[4]; };

// -------------------- fused MFMA GEMM (reads x/W in f32, converts in-register
// during LDS staging -- no xh/WhT intermediates, no prep kernel) + ELL
// scatter stripe (blockIdx.y == 24). x (5 MB) and W (768 KB) are L2-resident
// across the 24x/157x re-reads, so HBM reads ~ compulsory only.
#define AS(r, c) smem[(r) * 72 + (c)]
#define BS(r, c) smem[128 * 72 + (r) * 72 + (c)]
#define CS(r, c) smem[(r) * 136 + (c)]
__global__ __launch_bounds__(256) void k_gemm_mfma(
    const float* __restrict__ x,
    const float* __restrict__ Wl1, const float* __restrict__ Wr1,
    const float* __restrict__ Wsk,
    const float* __restrict__ bl1, const float* __restrict__ br1,
    const float* __restrict__ bsk, const float* __restrict__ b1,
    _Float16* __restrict__ xl1h, _Float16* __restrict__ xr1h,
    _Float16* __restrict__ sk1h,
    const int* __restrict__ ei, int* __restrict__ cursor,
    int* __restrict__ ell_off,
    int n, int ne, int m)
{
    extern __shared__ _Float16 smem[];   // 36864 B dynamic
    const int t  = threadIdx.x;

    if (blockIdx.y == gridDim.y - 1) {   // ---- ELL scatter stripe
        const int stride = gridDim.x * 256;
        for (int e = blockIdx.x * 256 + t; e < m; e += stride) {
            int s, d;
            if (e < ne) { s = ei[e]; d = ei[ne + e]; }
            else        { s = e - ne; d = s; }
            int c = atomicAdd(&cursor[d], 1);
            if (c < EW) ell_off[(d << 6) + c] = s << 11;  // byte off into f16 rows
        }
        return;
    }

    const int r0 = blockIdx.x * 128;
    const int c0 = blockIdx.y * 128;
    const float* __restrict__ W = (c0 < 1024) ? Wl1 : (c0 < 2048) ? Wr1 : Wsk;
    const int cw = c0 & 1023;

    // A tile: x[r0..r0+127][0..63] f32 -> f16 AS (coalesced float4 reads)
#pragma unroll
    for (int qq = 0; qq < 8; ++qq) {
        int idx = t + 256 * qq;               // 2048 float4 chunks
        int row = idx >> 4, k4 = (idx & 15) * 4;
        float4 v = make_float4(0.f, 0.f, 0.f, 0.f);
        if (r0 + row < n) v = *(const float4*)(x + (size_t)(r0 + row) * D + k4);
        union { _Float16 h[4]; uint2 u; } o;
        o.h[0] = (_Float16)v.x; o.h[1] = (_Float16)v.y;
        o.h[2] = (_Float16)v.z; o.h[3] = (_Float16)v.w;
        *(uint2*)(&AS(row, k4)) = o.u;
    }
    // B tile: W[k][cw+c] f32 -> f16 BS(c,k) transpose (coalesced along c)
#pragma unroll
    for (int qq = 0; qq < 8; ++qq) {
        int idx = t + 256 * qq;               // 2048 float4 chunks
        int k = idx >> 5, c4 = (idx & 31) * 4;
        float4 v = *(const float4*)(W + (size_t)k * F1 + cw + c4);
        BS(c4 + 0, k) = (_Float16)v.x;
        BS(c4 + 1, k) = (_Float16)v.y;
        BS(c4 + 2, k) = (_Float16)v.z;
        BS(c4 + 3, k) = (_Float16)v.w;
    }
    __syncthreads();

    const int wave = t >> 6, lane = t & 63;
    const int quad = lane >> 4, l16 = lane & 15;
    const int mw = (wave & 1) * 64, nw = (wave >> 1) * 64;

    f16x8 bfrag[4][2];
#pragma unroll
    for (int nt = 0; nt < 4; ++nt)
#pragma unroll
        for (int ks = 0; ks < 2; ++ks)
            bfrag[nt][ks] = *(const f16x8*)(&BS(nw + nt * 16 + l16, ks * 32 + quad * 8));

    f32x4 acc[4][4];
#pragma unroll
    for (int mt = 0; mt < 4; ++mt)
#pragma unroll
        for (int nt = 0; nt < 4; ++nt) acc[mt][nt] = (f32x4){0.f, 0.f, 0.f, 0.f};

#pragma unroll
    for (int mt = 0; mt < 4; ++mt) {
        f16x8 af[2];
#pragma unroll
        for (int ks = 0; ks < 2; ++ks)
            af[ks] = *(const f16x8*)(&AS(mw + mt * 16 + l16, ks * 32 + quad * 8));
#pragma unroll
        for (int nt = 0; nt < 4; ++nt)
#pragma unroll
            for (int ks = 0; ks < 2; ++ks)
                acc[mt][nt] = __builtin_amdgcn_mfma_f32_16x16x32_f16(
                    af[ks], bfrag[nt][ks], acc[mt][nt], 0, 0, 0);
    }

    const int which = c0 >> 10;                 // 0:xl 1:xr 2:skip
    const int csec  = c0 & 1023;
    __syncthreads();
#pragma unroll
    for (int nt = 0; nt < 4; ++nt) {
        int col = csec + nw + nt * 16 + l16;
        float bias = (which == 0) ? bl1[col] : (which == 1) ? br1[col]
                                             : (bsk[col] + b1[col]);
#pragma unroll
        for (int mt = 0; mt < 4; ++mt) {
#pragma unroll
            for (int r = 0; r < 4; ++r)
                CS(mw + mt * 16 + quad * 4 + r, nw + nt * 16 + l16) =
                    (_Float16)(acc[mt][nt][r] + bias);
        }
    }
    __syncthreads();

    _Float16* __restrict__ dst = (which == 0) ? xl1h : (which == 1) ? xr1h : sk1h;
#pragma unroll
    for (int it = 0; it < 8; ++it) {
        int idx = t + 256 * it;                 // 2048 chunks of 8 halfs
        int row = idx >> 4, c16 = idx & 15;
        int grow = r0 + row;
        if (grow < n) {
            u32x4 v = *(u32x4*)(&CS(row, c16 * 8));
            *(u32x4*)(dst + (size_t)grow * F1 + csec + c16 * 8) = v;
        }
    }
}

// ------- conv1 agg + softmax + skip + LayerNorm + ELU + conv2 proj (fused)
// ONE node per 128-thread block: two waves, one feature half (q) each.
// ELL edge offsets (address = f(node) only). Per-edge readlane -> SGPR base.
// THREE 4-edge banks with guarded refills (round-5 config: best measured,
// 68.0 us). conv1 is pinned at ~3.05 TB/s delivered across 5 structural
// variants (rounds 3-7) => BW-ceiling-bound on its ~209 MB of L2-miss
// traffic; further pipeline shaping is not the lever.
__global__ __launch_bounds__(128, 6) void k_conv1_ln(
    const int* __restrict__ cursor, const int* __restrict__ ell_off,
    const _Float16* __restrict__ xl1h, const _Float16* __restrict__ xr1h,
    const _Float16* __restrict__ sk1h,
    const float* __restrict__ att1,
    const float* __restrict__ g1, const float* __restrict__ beta1,
    const float* __restrict__ Wl2, const float* __restrict__ bl2,
    const float* __restrict__ Wr2, const float* __restrict__ br2,
    float* __restrict__ xl2, float* __restrict__ xr2, int n)
{
    __shared__ float sb[2][6];
    const int q    = threadIdx.x >> 6;          // wave id = feature half
    const int lane = threadIdx.x & 63;
    const int node = blockIdx.x;                // grid = n, always active
    const int cb  = q * 512 + lane * 8;
    const int cbB = cb * 2;                     // byte offset within row
    const h2 c02 = (h2){(_Float16)0.2f, (_Float16)0.2f};
    const char* __restrict__ xlB = (const char*)xl1h;

    // offset vector + degree: both depend only on node -> issue immediately
    int offv = ell_off[(node << 6) + lane];
    int deg  = cursor[node];
    deg = deg > EW ? EW : deg;                  // safety clamp (never for this graph)

    h2 xrv[4], at2[4], O[4];
    float ll = 0.f;
    float v[8];
    float s1 = 0.f, s2 = 0.f;

    {
        U4H u; u.u = *(const uint4*)(xr1h + (size_t)node * F1 + cb);
#pragma unroll
        for (int j = 0; j < 4; ++j) xrv[j] = u.h[j];
        float4 a0 = *(const float4*)(att1 + cb);
        float4 a1 = *(const float4*)(att1 + cb + 4);
        at2[0] = (h2){(_Float16)a0.x, (_Float16)a0.y};
        at2[1] = (h2){(_Float16)a0.z, (_Float16)a0.w};
        at2[2] = (h2){(_Float16)a1.x, (_Float16)a1.y};
        at2[3] = (h2){(_Float16)a1.z, (_Float16)a1.w};
#pragma unroll
        for (int j = 0; j < 4; ++j) O[j] = (h2){(_Float16)0.f, (_Float16)0.f};
    }

    auto edge = [&](const U4H& cur) {
        // two independent dot chains to break fdot2 serial dependency
        h2 s0 = cur.h[0] + xrv[0];
        h2 s1h = cur.h[1] + xrv[1];
        h2 s2h = cur.h[2] + xrv[2];
        h2 s3 = cur.h[3] + xrv[3];
        h2 r0 = __builtin_elementwise_max(s0, s0 * c02);
        h2 r1 = __builtin_elementwise_max(s1h, s1h * c02);
        h2 r2 = __builtin_elementwise_max(s2h, s2h * c02);
        h2 r3 = __builtin_elementwise_max(s3, s3 * c02);
        float pa = dot2f(r0, at2[0], 0.f);
        float pb = dot2f(r1, at2[1], 0.f);
        pa = dot2f(r2, at2[2], pa);
        pb = dot2f(r3, at2[3], pb);
        float p = red16(pa + pb);                           // per-head dot
        float w = __expf(p);                                // bounded logits
        ll += w;
        _Float16 wh = (_Float16)w;
        h2 wh2 = (h2){wh, wh};
#pragma unroll
        for (int j = 0; j < 4; ++j) O[j] = O[j] + wh2 * cur.h[j];  // v_pk_fma
    };

    // clamped load (dup-tail rows hit L1/L2)
    auto ld = [&](int k) -> U4H {
        int kk = k < deg ? k : deg - 1;
        int off = __builtin_amdgcn_readlane(offv, kk);  // uniform -> SGPR
        U4H u2; u2.u = *(const uint4*)(xlB + (unsigned)off + cbB);
        return u2;
    };
    {
        // bank prologue: A always; B/C behind uniform deg guards
        U4H A0 = ld(0), A1 = ld(1), A2 = ld(2), A3 = ld(3);
        U4H B0, B1, B2, B3, C0, C1, C2, C3;
        if (deg > 4) { B0 = ld(4); B1 = ld(5); B2 = ld(6); B3 = ld(7); }
        if (deg > 8) { C0 = ld(8); C1 = ld(9); C2 = ld(10); C3 = ld(11); }
        int i = 0;
        for (;;) {
            // consume A (edges i..i+3); banks B,C (8 gathers) in flight
            edge(A0);
            if (i + 1 < deg) edge(A1);
            if (i + 2 < deg) edge(A2);
            if (i + 3 < deg) edge(A3);
            i += 4;
            if (i >= deg) break;
            if (i + 8 < deg) { A0 = ld(i + 8); A1 = ld(i + 9);
                               A2 = ld(i + 10); A3 = ld(i + 11); }
            // consume B; banks C,A in flight
            edge(B0);
            if (i + 1 < deg) edge(B1);
            if (i + 2 < deg) edge(B2);
            if (i + 3 < deg) edge(B3);
            i += 4;
            if (i >= deg) break;
            if (i + 8 < deg) { B0 = ld(i + 8); B1 = ld(i + 9);
                               B2 = ld(i + 10); B3 = ld(i + 11); }
            // consume C; banks A,B in flight
            edge(C0);
            if (i + 1 < deg) edge(C1);
            if (i + 2 < deg) edge(C2);
            if (i + 3 < deg) edge(C3);
            i += 4;
            if (i >= deg) break;
            if (i + 8 < deg) { C0 = ld(i + 8); C1 = ld(i + 9);
                               C2 = ld(i + 10); C3 = ld(i + 11); }
        }
    }

    {
        float inv = 1.f / (ll + 1e-16f);
        U4H su; su.u = *(const uint4*)(sk1h + (size_t)node * F1 + cb);
#pragma unroll
        for (int j = 0; j < 4; ++j) {
            float xv0 = (float)su.h[j][0] + (float)O[j][0] * inv;
            float xv1 = (float)su.h[j][1] + (float)O[j][1] * inv;
            v[2 * j]     = xv0;
            v[2 * j + 1] = xv1;
            s1 += xv0 + xv1;
            s2 += xv0 * xv0 + xv1 * xv1;
        }
    }
#pragma unroll
    for (int off = 32; off > 0; off >>= 1) {
        s1 += __shfl_xor(s1, off);
        s2 += __shfl_xor(s2, off);
    }
    if (lane == 0) { sb[q][0] = s1; sb[q][1] = s2; }
    __syncthreads();
    float mu  = (sb[0][0] + sb[1][0]) * (1.f / 1024.f);
    float ms  = (sb[0][1] + sb[1][1]) * (1.f / 1024.f);
    float var = fmaxf(ms - mu * mu, 0.f);
    float inv = rsqrtf(var + 1e-5f);

    float p0 = 0.f, p1 = 0.f, p2 = 0.f, p3 = 0.f;
    {
        float4 gA = *(const float4*)(g1 + cb),    gB = *(const float4*)(g1 + cb + 4);
        float4 bA = *(const float4*)(beta1 + cb), bB = *(const float4*)(beta1 + cb + 4);
        float gv[8] = {gA.x, gA.y, gA.z, gA.w, gB.x, gB.y, gB.z, gB.w};
        float bv[8] = {bA.x, bA.y, bA.z, bA.w, bB.x, bB.y, bB.z, bB.w};
#pragma unroll
        for (int j = 0; j < 8; j += 2) {
            float4 wl = *(const float4*)(Wl2 + (cb + j) * 2);   // rows cb+j, cb+j+1
            float4 wr = *(const float4*)(Wr2 + (cb + j) * 2);
            float y0 = (v[j]   - mu) * inv * gv[j]   + bv[j];
            float y1 = (v[j+1] - mu) * inv * gv[j+1] + bv[j+1];
            float z0 = y0 > 0.f ? y0 : __expf(y0) - 1.f;       // ELU
            float z1 = y1 > 0.f ? y1 : __expf(y1) - 1.f;
            p0 += z0 * wl.x + z1 * wl.z;
            p1 += z0 * wl.y + z1 * wl.w;
            p2 += z0 * wr.x + z1 * wr.z;
            p3 += z0 * wr.y + z1 * wr.w;
        }
    }
#pragma unroll
    for (int off = 32; off > 0; off >>= 1) {
        p0 += __shfl_xor(p0, off); p1 += __shfl_xor(p1, off);
        p2 += __shfl_xor(p2, off); p3 += __shfl_xor(p3, off);
    }
    if (lane == 0) { sb[q][2] = p0; sb[q][3] = p1;
                     sb[q][4] = p2; sb[q][5] = p3; }
    __syncthreads();
    if (lane == 0 && q == 0) {
        *(float2*)(xl2 + 2 * node) =
            make_float2(sb[0][2] + sb[1][2] + bl2[0], sb[0][3] + sb[1][3] + bl2[1]);
        *(float2*)(xr2 + 2 * node) =
            make_float2(sb[0][4] + sb[1][4] + br2[0], sb[0][5] + sb[1][5] + br2[1]);
    }
}

// ------------ conv2: fused attention + softmax + agg, 1 thread/node (ELL)
__global__ __launch_bounds__(64) void k_conv2(
    const int* __restrict__ cursor, const int* __restrict__ ell_off,
    const float* __restrict__ xl2, const float* __restrict__ xr2,
    const float* __restrict__ att2, const float* __restrict__ b2,
    float* __restrict__ out2, int n)
{
    int d = blockIdx.x * blockDim.x + threadIdx.x;
    if (d >= n) return;
    float2 xr = *(const float2*)(xr2 + 2 * d);
    float a0w = att2[0], a1w = att2[1];
    float m = -INFINITY, l = 0.f, o0 = 0.f, o1 = 0.f;
    const int base = d << 6;
    int deg = cursor[d]; deg = deg > EW ? EW : deg;
    float2 pf[2];
    pf[0] = *(const float2*)(xl2 + (ell_off[base] >> 10));
    pf[1] = (1 < deg) ? *(const float2*)(xl2 + (ell_off[base + 1] >> 10)) : pf[0];
    for (int i = 0; i < deg; ++i) {
        float2 cur = pf[0];
        pf[0] = pf[1];
        if (i + 2 < deg) pf[1] = *(const float2*)(xl2 + (ell_off[base + i + 2] >> 10));
        float p = lrelu(cur.x + xr.x) * a0w + lrelu(cur.y + xr.y) * a1w;
        float nm = fmaxf(m, p);
        float sc = __expf(m - nm);
        float w  = __expf(p - nm);
        l = l * sc + w;
        o0 = o0 * sc + w * cur.x;
        o1 = o1 * sc + w * cur.y;
        m = nm;
    }
    float inv = 1.f / (l + 1e-16f);
    out2[2 * d + 0] = o0 * inv + b2[0];
    out2[2 * d + 1] = o1 * inv + b2[1];
}

// ----------------------------------------------------------------
extern "C" void kernel_launch(void* const* d_in, const int* in_sizes, int n_in,
                              void* d_out, int out_size, void* d_ws, size_t ws_size,
                              hipStream_t stream)
{
    const float* x     = (const float*)d_in[0];
    const int*   ei    = (const int*)  d_in[1];
    const float* Wl1   = (const float*)d_in[2];
    const float* bl1   = (const float*)d_in[3];
    const float* Wr1   = (const float*)d_in[4];
    const float* br1   = (const float*)d_in[5];
    const float* att1  = (const float*)d_in[6];
    const float* b1    = (const float*)d_in[7];
    const float* Wsk   = (const float*)d_in[8];
    const float* bsk   = (const float*)d_in[9];
    const float* g1    = (const float*)d_in[10];
    const float* beta1 = (const float*)d_in[11];
    const float* Wl2   = (const float*)d_in[12];
    const float* bl2   = (const float*)d_in[13];
    const float* Wr2   = (const float*)d_in[14];
    const float* br2   = (const float*)d_in[15];
    const float* att2  = (const float*)d_in[16];
    const float* b2    = (const float*)d_in[17];

    const int n  = in_sizes[0] / D;    // 20000
    const int ne = in_sizes[1] / 2;    // 160000
    const int m  = ne + n;             // incl. self loops

    float* ws = (float*)d_ws;
    size_t o = 0;
    _Float16* xl1h = (_Float16*)(ws + o); o += (size_t)n * F1 / 2;
    _Float16* xr1h = (_Float16*)(ws + o); o += (size_t)n * F1 / 2;
    _Float16* sk1h = (_Float16*)(ws + o); o += (size_t)n * F1 / 2;
    float* xl2    = ws + o; o += (size_t)n * 2;
    float* xr2    = ws + o; o += (size_t)n * 2;
    int* cursor   = (int*)(ws + o); o += (size_t)n;
    int* ell_off  = (int*)(ws + o); o += (size_t)n * EW;
    float* out2   = (float*)d_out;

    // --- zero ELL cursors ---
    (void)hipMemsetAsync(cursor, 0, (size_t)n * sizeof(int), stream);

    // --- fused MFMA GEMM (f32 in-register cast staging) + ELL scatter stripe ---
    dim3 gg((n + 127) / 128, NTOT / 128 + 1);
    k_gemm_mfma<<<gg, 256, 36864, stream>>>(x, Wl1, Wr1, Wsk,
                                            bl1, br1, bsk, b1,
                                            xl1h, xr1h, sk1h,
                                            ei, cursor, ell_off,
                                            n, ne, m);

    // --- conv1 agg + LN + ELU + conv2 projections (1 node / 128-thr block) ---
    k_conv1_ln<<<n, 128, 0, stream>>>(cursor, ell_off, xl1h, xr1h, sk1h,
                                      att1, g1, beta1, Wl2, bl2, Wr2, br2,
                                      xl2, xr2, n);

    // --- conv2 ---
    k_conv2<<<(n + 63) / 64, 64, 0, stream>>>(cursor, ell_off, xl2, xr2, att2, b2, out2, n);
}

// Round 9
// 205.552 us; speedup vs baseline: 1.0674x; 1.0674x over previous
//
#include <hip/hip_runtime.h>
#include <hip/hip_bf16.h>
#include <hip/hip_fp16.h>
#include <math.h>

static constexpr int D  = 64;     // input dim
static constexpr int F1 = 1024;   // H1*C1
static constexpr int NTOT = 3072; // 3 fused GEMM outputs
static constexpr int EW  = 64;    // ELL width (max deg; Poisson(8)+1 graph)

typedef _Float16 f16x8 __attribute__((ext_vector_type(8)));  // MFMA A/B frag
typedef _Float16 h2    __attribute__((ext_vector_type(2)));  // packed pair
typedef float    f32x4 __attribute__((ext_vector_type(4)));
typedef unsigned int u32x4 __attribute__((ext_vector_type(4)));

__device__ __forceinline__ float lrelu(float x) { return x > 0.f ? x : 0.2f * x; }

// dot of two f16 pairs, f32 accumulate (v_dot2_f32_f16 when available)
__device__ __forceinline__ float dot2f(h2 a, h2 b, float c) {
#if __has_builtin(__builtin_amdgcn_fdot2)
    return __builtin_amdgcn_fdot2(a, b, c, false);
#else
    return c + (float)a[0] * (float)b[0] + (float)a[1] * (float)b[1];
#endif
}

// 16-lane sum via DPP row ops (VALU pipe): xor1=0xB1, xor2=0x4E,
// xor4=row_half_mirror(0x141), xor8=row_mirror(0x140).
__device__ __forceinline__ float red16(float p) {
    int v = __builtin_bit_cast(int, p);
    p += __builtin_bit_cast(float, __builtin_amdgcn_mov_dpp(v, 0xB1, 0xF, 0xF, true));
    v = __builtin_bit_cast(int, p);
    p += __builtin_bit_cast(float, __builtin_amdgcn_mov_dpp(v, 0x4E, 0xF, 0xF, true));
    v = __builtin_bit_cast(int, p);
    p += __builtin_bit_cast(float, __builtin_amdgcn_mov_dpp(v, 0x141, 0xF, 0xF, true));
    v = __builtin_bit_cast(int, p);
    p += __builtin_bit_cast(float, __builtin_amdgcn_mov_dpp(v, 0x140, 0xF, 0xF, true));
    return p;
}

union U4H { uint4 u; h2 h[4]; };

// ------ fused prep: {x->f16 cast | ELL scatter (count+place in one atomic) | W pack}
// W pack done ONCE here (24 blocks): its LDS-transpose bank conflicts are
// amortized. Round 8 showed fusing it into the GEMM amplifies the conflict
// cost 157x (SQ_LDS_BANK_CONFLICT 0 -> 1.6e7, GEMM 45 -> 70 us).
__global__ __launch_bounds__(256) void k_prep(
    const float* __restrict__ x, _Float16* __restrict__ xh,
    const int* __restrict__ ei, int* __restrict__ cursor,
    int* __restrict__ ell_off,
    const float* __restrict__ Wl1, const float* __restrict__ Wr1,
    const float* __restrict__ Wsk, _Float16* __restrict__ WhT,
    int n, int ne, int m, int castB, int degB)
{
    __shared__ _Float16 wt[128 * 72];
    const int b = blockIdx.x;
    if (b < castB) {
        int t = b * 256 + threadIdx.x;
        int ncast = (n * D) / 4;               // float4 chunks of x
        if (t < ncast) {
            float4 v = ((const float4*)x)[t];
            union { _Float16 h[4]; uint2 u; } o;
            o.h[0] = (_Float16)v.x; o.h[1] = (_Float16)v.y;
            o.h[2] = (_Float16)v.z; o.h[3] = (_Float16)v.w;
            *(uint2*)(xh + (size_t)t * 4) = o.u;
        }
    } else if (b < castB + degB) {
        // ELL scatter: one atomic yields slot AND (post-pass) degree
        int t = (b - castB) * 256 + threadIdx.x;
        if (t < m) {
            int s, d;
            if (t < ne) { s = ei[t]; d = ei[ne + t]; }
            else        { s = t - ne; d = s; }
            int c = atomicAdd(&cursor[d], 1);
            if (c < EW) ell_off[(d << 6) + c] = s << 11;  // byte off into f16 rows
        }
    } else {
        // W^T pack via LDS transpose (coalesced global reads)
        const int t = threadIdx.x;
        const int c0 = (b - castB - degB) * 128;     // global col in [0,3072)
        const float* __restrict__ W = (c0 < 1024) ? Wl1 : (c0 < 2048) ? Wr1 : Wsk;
        const int cw = c0 & 1023;
#pragma unroll
        for (int q = 0; q < 8; ++q) {
            int idx = t + 256 * q;                   // 2048 float4 chunks
            int k = idx >> 5, c4 = (idx & 31) * 4;
            float4 v = *(const float4*)(W + (size_t)k * F1 + cw + c4);
            wt[(c4 + 0) * 72 + k] = (_Float16)v.x;
            wt[(c4 + 1) * 72 + k] = (_Float16)v.y;
            wt[(c4 + 2) * 72 + k] = (_Float16)v.z;
            wt[(c4 + 3) * 72 + k] = (_Float16)v.w;
        }
        __syncthreads();
#pragma unroll
        for (int q = 0; q < 4; ++q) {
            int idx = t + 256 * q;                   // 1024 chunks of 8 f16
            int c = idx >> 3, k0 = (idx & 7) * 8;
            uint4 v = *(const uint4*)(&wt[c * 72 + k0]);
            *(uint4*)(WhT + (size_t)(c0 + c) * 64 + k0) = v;
        }
    }
}

// -------------------- MFMA GEMM (f16), 128x128 tiles, pure, packed inputs
#define AS(r, c) smem[(r) * 72 + (c)]
#define BS(r, c) smem[128 * 72 + (r) * 72 + (c)]
#define CS(r, c) smem[(r) * 136 + (c)]
__global__ __launch_bounds__(256) void k_gemm_mfma(
    const _Float16* __restrict__ xh, const _Float16* __restrict__ WhT,
    const float* __restrict__ bl1, const float* __restrict__ br1,
    const float* __restrict__ bsk, const float* __restrict__ b1,
    _Float16* __restrict__ xl1h, _Float16* __restrict__ xr1h,
    _Float16* __restrict__ sk1h, int n)
{
    extern __shared__ _Float16 smem[];   // 36864 B dynamic
    const int t  = threadIdx.x;
    const int r0 = blockIdx.x * 128;
    const int c0 = blockIdx.y * 128;

#pragma unroll
    for (int q = 0; q < 4; ++q) {
        int c = t + 256 * q;            // 1024 chunks of 16B
        int row = c >> 3, off = (c & 7) * 8;
        uint4 v = make_uint4(0, 0, 0, 0);
        if (r0 + row < n) v = *(const uint4*)(xh + (size_t)(r0 + row) * 64 + off);
        *(uint4*)(&AS(row, off)) = v;
        uint4 w = *(const uint4*)(WhT + (size_t)(c0 + row) * 64 + off);
        *(uint4*)(&BS(row, off)) = w;
    }
    __syncthreads();

    const int wave = t >> 6, lane = t & 63;
    const int quad = lane >> 4, l16 = lane & 15;
    const int mw = (wave & 1) * 64, nw = (wave >> 1) * 64;

    f16x8 bfrag[4][2];
#pragma unroll
    for (int nt = 0; nt < 4; ++nt)
#pragma unroll
        for (int ks = 0; ks < 2; ++ks)
            bfrag[nt][ks] = *(const f16x8*)(&BS(nw + nt * 16 + l16, ks * 32 + quad * 8));

    f32x4 acc[4][4];
#pragma unroll
    for (int mt = 0; mt < 4; ++mt)
#pragma unroll
        for (int nt = 0; nt < 4; ++nt) acc[mt][nt] = (f32x4){0.f, 0.f, 0.f, 0.f};

#pragma unroll
    for (int mt = 0; mt < 4; ++mt) {
        f16x8 af[2];
#pragma unroll
        for (int ks = 0; ks < 2; ++ks)
            af[ks] = *(const f16x8*)(&AS(mw + mt * 16 + l16, ks * 32 + quad * 8));
#pragma unroll
        for (int nt = 0; nt < 4; ++nt)
#pragma unroll
            for (int ks = 0; ks < 2; ++ks)
                acc[mt][nt] = __builtin_amdgcn_mfma_f32_16x16x32_f16(
                    af[ks], bfrag[nt][ks], acc[mt][nt], 0, 0, 0);
    }

    const int which = c0 >> 10;                 // 0:xl 1:xr 2:skip
    const int csec  = c0 & 1023;
    __syncthreads();
#pragma unroll
    for (int nt = 0; nt < 4; ++nt) {
        int col = csec + nw + nt * 16 + l16;
        float bias = (which == 0) ? bl1[col] : (which == 1) ? br1[col]
                                             : (bsk[col] + b1[col]);
#pragma unroll
        for (int mt = 0; mt < 4; ++mt) {
#pragma unroll
            for (int r = 0; r < 4; ++r)
                CS(mw + mt * 16 + quad * 4 + r, nw + nt * 16 + l16) =
                    (_Float16)(acc[mt][nt][r] + bias);
        }
    }
    __syncthreads();

    _Float16* __restrict__ dst = (which == 0) ? xl1h : (which == 1) ? xr1h : sk1h;
#pragma unroll
    for (int it = 0; it < 8; ++it) {
        int idx = t + 256 * it;                 // 2048 chunks of 8 halfs
        int row = idx >> 4, c16 = idx & 15;
        int grow = r0 + row;
        if (grow < n) {
            u32x4 v = *(u32x4*)(&CS(row, c16 * 8));
            *(u32x4*)(dst + (size_t)grow * F1 + csec + c16 * 8) = v;
        }
    }
}

// ------- conv1 agg + softmax + skip + LayerNorm + ELU + conv2 proj (fused)
// ONE node per 128-thread block: two waves, one feature half (q) each.
// ELL edge offsets (address = f(node) only). Per-edge readlane -> SGPR base.
// THREE 4-edge banks with guarded refills (round-5 config: best measured,
// 68.0 us). conv1 is pinned at ~3.2 TB/s delivered across 5 structural
// variants (rounds 3-8) => BW-ceiling-bound on its ~209 MB of L2-miss
// traffic; further pipeline shaping is not the lever.
__global__ __launch_bounds__(128, 6) void k_conv1_ln(
    const int* __restrict__ cursor, const int* __restrict__ ell_off,
    const _Float16* __restrict__ xl1h, const _Float16* __restrict__ xr1h,
    const _Float16* __restrict__ sk1h,
    const float* __restrict__ att1,
    const float* __restrict__ g1, const float* __restrict__ beta1,
    const float* __restrict__ Wl2, const float* __restrict__ bl2,
    const float* __restrict__ Wr2, const float* __restrict__ br2,
    float* __restrict__ xl2, float* __restrict__ xr2, int n)
{
    __shared__ float sb[2][6];
    const int q    = threadIdx.x >> 6;          // wave id = feature half
    const int lane = threadIdx.x & 63;
    const int node = blockIdx.x;                // grid = n, always active
    const int cb  = q * 512 + lane * 8;
    const int cbB = cb * 2;                     // byte offset within row
    const h2 c02 = (h2){(_Float16)0.2f, (_Float16)0.2f};
    const char* __restrict__ xlB = (const char*)xl1h;

    // offset vector + degree: both depend only on node -> issue immediately
    int offv = ell_off[(node << 6) + lane];
    int deg  = cursor[node];
    deg = deg > EW ? EW : deg;                  // safety clamp (never for this graph)

    h2 xrv[4], at2[4], O[4];
    float ll = 0.f;
    float v[8];
    float s1 = 0.f, s2 = 0.f;

    {
        U4H u; u.u = *(const uint4*)(xr1h + (size_t)node * F1 + cb);
#pragma unroll
        for (int j = 0; j < 4; ++j) xrv[j] = u.h[j];
        float4 a0 = *(const float4*)(att1 + cb);
        float4 a1 = *(const float4*)(att1 + cb + 4);
        at2[0] = (h2){(_Float16)a0.x, (_Float16)a0.y};
        at2[1] = (h2){(_Float16)a0.z, (_Float16)a0.w};
        at2[2] = (h2){(_Float16)a1.x, (_Float16)a1.y};
        at2[3] = (h2){(_Float16)a1.z, (_Float16)a1.w};
#pragma unroll
        for (int j = 0; j < 4; ++j) O[j] = (h2){(_Float16)0.f, (_Float16)0.f};
    }

    auto edge = [&](const U4H& cur) {
        // two independent dot chains to break fdot2 serial dependency
        h2 s0 = cur.h[0] + xrv[0];
        h2 s1h = cur.h[1] + xrv[1];
        h2 s2h = cur.h[2] + xrv[2];
        h2 s3 = cur.h[3] + xrv[3];
        h2 r0 = __builtin_elementwise_max(s0, s0 * c02);
        h2 r1 = __builtin_elementwise_max(s1h, s1h * c02);
        h2 r2 = __builtin_elementwise_max(s2h, s2h * c02);
        h2 r3 = __builtin_elementwise_max(s3, s3 * c02);
        float pa = dot2f(r0, at2[0], 0.f);
        float pb = dot2f(r1, at2[1], 0.f);
        pa = dot2f(r2, at2[2], pa);
        pb = dot2f(r3, at2[3], pb);
        float p = red16(pa + pb);                           // per-head dot
        float w = __expf(p);                                // bounded logits
        ll += w;
        _Float16 wh = (_Float16)w;
        h2 wh2 = (h2){wh, wh};
#pragma unroll
        for (int j = 0; j < 4; ++j) O[j] = O[j] + wh2 * cur.h[j];  // v_pk_fma
    };

    // clamped load (dup-tail rows hit L1/L2)
    auto ld = [&](int k) -> U4H {
        int kk = k < deg ? k : deg - 1;
        int off = __builtin_amdgcn_readlane(offv, kk);  // uniform -> SGPR
        U4H u2; u2.u = *(const uint4*)(xlB + (unsigned)off + cbB);
        return u2;
    };
    {
        // bank prologue: A always; B/C behind uniform deg guards
        U4H A0 = ld(0), A1 = ld(1), A2 = ld(2), A3 = ld(3);
        U4H B0, B1, B2, B3, C0, C1, C2, C3;
        if (deg > 4) { B0 = ld(4); B1 = ld(5); B2 = ld(6); B3 = ld(7); }
        if (deg > 8) { C0 = ld(8); C1 = ld(9); C2 = ld(10); C3 = ld(11); }
        int i = 0;
        for (;;) {
            // consume A (edges i..i+3); banks B,C (8 gathers) in flight
            edge(A0);
            if (i + 1 < deg) edge(A1);
            if (i + 2 < deg) edge(A2);
            if (i + 3 < deg) edge(A3);
            i += 4;
            if (i >= deg) break;
            if (i + 8 < deg) { A0 = ld(i + 8); A1 = ld(i + 9);
                               A2 = ld(i + 10); A3 = ld(i + 11); }
            // consume B; banks C,A in flight
            edge(B0);
            if (i + 1 < deg) edge(B1);
            if (i + 2 < deg) edge(B2);
            if (i + 3 < deg) edge(B3);
            i += 4;
            if (i >= deg) break;
            if (i + 8 < deg) { B0 = ld(i + 8); B1 = ld(i + 9);
                               B2 = ld(i + 10); B3 = ld(i + 11); }
            // consume C; banks A,B in flight
            edge(C0);
            if (i + 1 < deg) edge(C1);
            if (i + 2 < deg) edge(C2);
            if (i + 3 < deg) edge(C3);
            i += 4;
            if (i >= deg) break;
            if (i + 8 < deg) { C0 = ld(i + 8); C1 = ld(i + 9);
                               C2 = ld(i + 10); C3 = ld(i + 11); }
        }
    }

    {
        float inv = 1.f / (ll + 1e-16f);
        U4H su; su.u = *(const uint4*)(sk1h + (size_t)node * F1 + cb);
#pragma unroll
        for (int j = 0; j < 4; ++j) {
            float xv0 = (float)su.h[j][0] + (float)O[j][0] * inv;
            float xv1 = (float)su.h[j][1] + (float)O[j][1] * inv;
            v[2 * j]     = xv0;
            v[2 * j + 1] = xv1;
            s1 += xv0 + xv1;
            s2 += xv0 * xv0 + xv1 * xv1;
        }
    }
#pragma unroll
    for (int off = 32; off > 0; off >>= 1) {
        s1 += __shfl_xor(s1, off);
        s2 += __shfl_xor(s2, off);
    }
    if (lane == 0) { sb[q][0] = s1; sb[q][1] = s2; }
    __syncthreads();
    float mu  = (sb[0][0] + sb[1][0]) * (1.f / 1024.f);
    float ms  = (sb[0][1] + sb[1][1]) * (1.f / 1024.f);
    float var = fmaxf(ms - mu * mu, 0.f);
    float inv = rsqrtf(var + 1e-5f);

    float p0 = 0.f, p1 = 0.f, p2 = 0.f, p3 = 0.f;
    {
        float4 gA = *(const float4*)(g1 + cb),    gB = *(const float4*)(g1 + cb + 4);
        float4 bA = *(const float4*)(beta1 + cb), bB = *(const float4*)(beta1 + cb + 4);
        float gv[8] = {gA.x, gA.y, gA.z, gA.w, gB.x, gB.y, gB.z, gB.w};
        float bv[8] = {bA.x, bA.y, bA.z, bA.w, bB.x, bB.y, bB.z, bB.w};
#pragma unroll
        for (int j = 0; j < 8; j += 2) {
            float4 wl = *(const float4*)(Wl2 + (cb + j) * 2);   // rows cb+j, cb+j+1
            float4 wr = *(const float4*)(Wr2 + (cb + j) * 2);
            float y0 = (v[j]   - mu) * inv * gv[j]   + bv[j];
            float y1 = (v[j+1] - mu) * inv * gv[j+1] + bv[j+1];
            float z0 = y0 > 0.f ? y0 : __expf(y0) - 1.f;       // ELU
            float z1 = y1 > 0.f ? y1 : __expf(y1) - 1.f;
            p0 += z0 * wl.x + z1 * wl.z;
            p1 += z0 * wl.y + z1 * wl.w;
            p2 += z0 * wr.x + z1 * wr.z;
            p3 += z0 * wr.y + z1 * wr.w;
        }
    }
#pragma unroll
    for (int off = 32; off > 0; off >>= 1) {
        p0 += __shfl_xor(p0, off); p1 += __shfl_xor(p1, off);
        p2 += __shfl_xor(p2, off); p3 += __shfl_xor(p3, off);
    }
    if (lane == 0) { sb[q][2] = p0; sb[q][3] = p1;
                     sb[q][4] = p2; sb[q][5] = p3; }
    __syncthreads();
    if (lane == 0 && q == 0) {
        *(float2*)(xl2 + 2 * node) =
            make_float2(sb[0][2] + sb[1][2] + bl2[0], sb[0][3] + sb[1][3] + bl2[1]);
        *(float2*)(xr2 + 2 * node) =
            make_float2(sb[0][4] + sb[1][4] + br2[0], sb[0][5] + sb[1][5] + br2[1]);
    }
}

// ------------ conv2: ONE WAVE per node, lane = ELL edge slot.
// Coalesced ell_off load (node*64+lane), per-lane logit, shfl max/sum
// reductions. Replaces the 1-thread/node serial walk (313 waves chip-wide,
// dependent-load chain) with 20000 independent waves -- probing whether
// conv2 was the hidden ~75 us/iteration the top-5 never showed.
__global__ __launch_bounds__(64) void k_conv2(
    const int* __restrict__ cursor, const int* __restrict__ ell_off,
    const float* __restrict__ xl2, const float* __restrict__ xr2,
    const float* __restrict__ att2, const float* __restrict__ b2,
    float* __restrict__ out2, int n)
{
    const int node = blockIdx.x;
    const int lane = threadIdx.x;
    int deg = cursor[node]; deg = deg > EW ? EW : deg;
    float2 xr = *(const float2*)(xr2 + 2 * node);
    float a0w = att2[0], a1w = att2[1];
    int off = ell_off[(node << 6) + lane];      // coalesced
    bool valid = lane < deg;
    float2 cur = make_float2(0.f, 0.f);
    if (valid) cur = *(const float2*)(xl2 + (off >> 10));
    float p = valid ? lrelu(cur.x + xr.x) * a0w + lrelu(cur.y + xr.y) * a1w
                    : -INFINITY;
    float m = p;
#pragma unroll
    for (int o = 32; o > 0; o >>= 1) m = fmaxf(m, __shfl_xor(m, o));
    float w = valid ? __expf(p - m) : 0.f;
    float l = w, o0 = w * cur.x, o1 = w * cur.y;
#pragma unroll
    for (int o = 32; o > 0; o >>= 1) {
        l  += __shfl_xor(l, o);
        o0 += __shfl_xor(o0, o);
        o1 += __shfl_xor(o1, o);
    }
    if (lane == 0) {
        float inv = 1.f / (l + 1e-16f);
        *(float2*)(out2 + 2 * node) = make_float2(o0 * inv + b2[0],
                                                  o1 * inv + b2[1]);
    }
}

// ----------------------------------------------------------------
extern "C" void kernel_launch(void* const* d_in, const int* in_sizes, int n_in,
                              void* d_out, int out_size, void* d_ws, size_t ws_size,
                              hipStream_t stream)
{
    const float* x     = (const float*)d_in[0];
    const int*   ei    = (const int*)  d_in[1];
    const float* Wl1   = (const float*)d_in[2];
    const float* bl1   = (const float*)d_in[3];
    const float* Wr1   = (const float*)d_in[4];
    const float* br1   = (const float*)d_in[5];
    const float* att1  = (const float*)d_in[6];
    const float* b1    = (const float*)d_in[7];
    const float* Wsk   = (const float*)d_in[8];
    const float* bsk   = (const float*)d_in[9];
    const float* g1    = (const float*)d_in[10];
    const float* beta1 = (const float*)d_in[11];
    const float* Wl2   = (const float*)d_in[12];
    const float* bl2   = (const float*)d_in[13];
    const float* Wr2   = (const float*)d_in[14];
    const float* br2   = (const float*)d_in[15];
    const float* att2  = (const float*)d_in[16];
    const float* b2    = (const float*)d_in[17];

    const int n  = in_sizes[0] / D;    // 20000
    const int ne = in_sizes[1] / 2;    // 160000
    const int m  = ne + n;             // incl. self loops

    float* ws = (float*)d_ws;
    size_t o = 0;
    _Float16* xl1h = (_Float16*)(ws + o); o += (size_t)n * F1 / 2;
    _Float16* xr1h = (_Float16*)(ws + o); o += (size_t)n * F1 / 2;
    _Float16* sk1h = (_Float16*)(ws + o); o += (size_t)n * F1 / 2;
    _Float16* xh   = (_Float16*)(ws + o); o += (size_t)n * D / 2;
    _Float16* WhT  = (_Float16*)(ws + o); o += (size_t)NTOT * 64 / 2;
    float* xl2    = ws + o; o += (size_t)n * 2;
    float* xr2    = ws + o; o += (size_t)n * 2;
    int* cursor   = (int*)(ws + o); o += (size_t)n;
    int* ell_off  = (int*)(ws + o); o += (size_t)n * EW;
    float* out2   = (float*)d_out;

    // --- graph structure (ELL) + f16 prep + W pack (one fused launch) ---
    (void)hipMemsetAsync(cursor, 0, (size_t)n * sizeof(int), stream);
    const int castB = ((n * D) / 4 + 255) / 256;   // 1250
    const int degB  = (m + 255) / 256;             // 704
    k_prep<<<castB + degB + NTOT / 128, 256, 0, stream>>>(
        x, xh, ei, cursor, ell_off, Wl1, Wr1, Wsk, WhT, n, ne, m, castB, degB);

    // --- MFMA GEMM (pure, packed inputs) ---
    dim3 gg((n + 127) / 128, NTOT / 128);
    k_gemm_mfma<<<gg, 256, 36864, stream>>>(xh, WhT, bl1, br1, bsk, b1,
                                            xl1h, xr1h, sk1h, n);

    // --- conv1 agg + LN + ELU + conv2 projections (1 node / 128-thr block) ---
    k_conv1_ln<<<n, 128, 0, stream>>>(cursor, ell_off, xl1h, xr1h, sk1h,
                                      att1, g1, beta1, Wl2, bl2, Wr2, br2,
                                      xl2, xr2, n);

    // --- conv2 (1 wave / node) ---
    k_conv2<<<n, 64, 0, stream>>>(cursor, ell_off, xl2, xr2, att2, b2, out2, n);
}

// Round 12
// 202.653 us; speedup vs baseline: 1.0827x; 1.0143x over previous
//
#include <hip/hip_runtime.h>
#include <hip/hip_bf16.h>
#include <hip/hip_fp16.h>
#include <math.h>

static constexpr int D  = 64;     // input dim
static constexpr int F1 = 1024;   // H1*C1
static constexpr int NTOT = 3072; // 3 fused GEMM outputs
static constexpr int EW  = 64;    // ELL width (max deg; Poisson(8)+1 graph)

typedef _Float16 f16x8 __attribute__((ext_vector_type(8)));  // MFMA A/B frag
typedef _Float16 h2    __attribute__((ext_vector_type(2)));  // packed pair
typedef float    f32x4 __attribute__((ext_vector_type(4)));
typedef unsigned int u32x4 __attribute__((ext_vector_type(4)));

__device__ __forceinline__ float lrelu(float x) { return x > 0.f ? x : 0.2f * x; }

// dot of two f16 pairs, f32 accumulate (v_dot2_f32_f16 when available)
__device__ __forceinline__ float dot2f(h2 a, h2 b, float c) {
#if __has_builtin(__builtin_amdgcn_fdot2)
    return __builtin_amdgcn_fdot2(a, b, c, false);
#else
    return c + (float)a[0] * (float)b[0] + (float)a[1] * (float)b[1];
#endif
}

// 16-lane sum via DPP row ops (VALU pipe): xor1=0xB1, xor2=0x4E,
// xor4=row_half_mirror(0x141), xor8=row_mirror(0x140).
__device__ __forceinline__ float red16(float p) {
    int v = __builtin_bit_cast(int, p);
    p += __builtin_bit_cast(float, __builtin_amdgcn_mov_dpp(v, 0xB1, 0xF, 0xF, true));
    v = __builtin_bit_cast(int, p);
    p += __builtin_bit_cast(float, __builtin_amdgcn_mov_dpp(v, 0x4E, 0xF, 0xF, true));
    v = __builtin_bit_cast(int, p);
    p += __builtin_bit_cast(float, __builtin_amdgcn_mov_dpp(v, 0x141, 0xF, 0xF, true));
    v = __builtin_bit_cast(int, p);
    p += __builtin_bit_cast(float, __builtin_amdgcn_mov_dpp(v, 0x140, 0xF, 0xF, true));
    return p;
}

union U4H { uint4 u; h2 h[4]; };

// ------ fused prep: {x->f16 cast | ELL scatter (count+place in one atomic) | W pack}
__global__ __launch_bounds__(256) void k_prep(
    const float* __restrict__ x, _Float16* __restrict__ xh,
    const int* __restrict__ ei, int* __restrict__ cursor,
    int* __restrict__ ell_off,
    const float* __restrict__ Wl1, const float* __restrict__ Wr1,
    const float* __restrict__ Wsk, _Float16* __restrict__ WhT,
    int n, int ne, int m, int castB, int degB)
{
    __shared__ _Float16 wt[128 * 72];
    const int b = blockIdx.x;
    if (b < castB) {
        int t = b * 256 + threadIdx.x;
        int ncast = (n * D) / 4;               // float4 chunks of x
        if (t < ncast) {
            float4 v = ((const float4*)x)[t];
            union { _Float16 h[4]; uint2 u; } o;
            o.h[0] = (_Float16)v.x; o.h[1] = (_Float16)v.y;
            o.h[2] = (_Float16)v.z; o.h[3] = (_Float16)v.w;
            *(uint2*)(xh + (size_t)t * 4) = o.u;
        }
    } else if (b < castB + degB) {
        // ELL scatter: one atomic yields slot AND (post-pass) degree
        int t = (b - castB) * 256 + threadIdx.x;
        if (t < m) {
            int s, d;
            if (t < ne) { s = ei[t]; d = ei[ne + t]; }
            else        { s = t - ne; d = s; }
            int c = atomicAdd(&cursor[d], 1);
            if (c < EW) ell_off[(d << 6) + c] = s << 11;  // byte off into f16 rows
        }
    } else {
        // W^T pack via LDS transpose (coalesced global reads)
        const int t = threadIdx.x;
        const int c0 = (b - castB - degB) * 128;     // global col in [0,3072)
        const float* __restrict__ W = (c0 < 1024) ? Wl1 : (c0 < 2048) ? Wr1 : Wsk;
        const int cw = c0 & 1023;
#pragma unroll
        for (int q = 0; q < 8; ++q) {
            int idx = t + 256 * q;                   // 2048 float4 chunks
            int k = idx >> 5, c4 = (idx & 31) * 4;
            float4 v = *(const float4*)(W + (size_t)k * F1 + cw + c4);
            wt[(c4 + 0) * 72 + k] = (_Float16)v.x;
            wt[(c4 + 1) * 72 + k] = (_Float16)v.y;
            wt[(c4 + 2) * 72 + k] = (_Float16)v.z;
            wt[(c4 + 3) * 72 + k] = (_Float16)v.w;
        }
        __syncthreads();
#pragma unroll
        for (int q = 0; q < 4; ++q) {
            int idx = t + 256 * q;                   // 1024 chunks of 8 f16
            int c = idx >> 3, k0 = (idx & 7) * 8;
            uint4 v = *(const uint4*)(&wt[c * 72 + k0]);
            *(uint4*)(WhT + (size_t)(c0 + c) * 64 + k0) = v;
        }
    }
}

// -------------------- MFMA GEMM (f16), 128x128 tiles, pure
#define AS(r, c) smem[(r) * 72 + (c)]
#define BS(r, c) smem[128 * 72 + (r) * 72 + (c)]
#define CS(r, c) smem[(r) * 136 + (c)]
__global__ __launch_bounds__(256) void k_gemm_mfma(
    const _Float16* __restrict__ xh, const _Float16* __restrict__ WhT,
    const float* __restrict__ bl1, const float* __restrict__ br1,
    const float* __restrict__ bsk, const float* __restrict__ b1,
    _Float16* __restrict__ xl1h, _Float16* __restrict__ xr1h,
    _Float16* __restrict__ sk1h, int n)
{
    extern __shared__ _Float16 smem[];   // 36864 B dynamic
    const int t  = threadIdx.x;
    const int r0 = blockIdx.x * 128;
    const int c0 = blockIdx.y * 128;

#pragma unroll
    for (int q = 0; q < 4; ++q) {
        int c = t + 256 * q;            // 1024 chunks of 16B
        int row = c >> 3, off = (c & 7) * 8;
        uint4 v = make_uint4(0, 0, 0, 0);
        if (r0 + row < n) v = *(const uint4*)(xh + (size_t)(r0 + row) * 64 + off);
        *(uint4*)(&AS(row, off)) = v;
        uint4 w = *(const uint4*)(WhT + (size_t)(c0 + row) * 64 + off);
        *(uint4*)(&BS(row, off)) = w;
    }
    __syncthreads();

    const int wave = t >> 6, lane = t & 63;
    const int quad = lane >> 4, l16 = lane & 15;
    const int mw = (wave & 1) * 64, nw = (wave >> 1) * 64;

    f16x8 bfrag[4][2];
#pragma unroll
    for (int nt = 0; nt < 4; ++nt)
#pragma unroll
        for (int ks = 0; ks < 2; ++ks)
            bfrag[nt][ks] = *(const f16x8*)(&BS(nw + nt * 16 + l16, ks * 32 + quad * 8));

    f32x4 acc[4][4];
#pragma unroll
    for (int mt = 0; mt < 4; ++mt)
#pragma unroll
        for (int nt = 0; nt < 4; ++nt) acc[mt][nt] = (f32x4){0.f, 0.f, 0.f, 0.f};

#pragma unroll
    for (int mt = 0; mt < 4; ++mt) {
        f16x8 af[2];
#pragma unroll
        for (int ks = 0; ks < 2; ++ks)
            af[ks] = *(const f16x8*)(&AS(mw + mt * 16 + l16, ks * 32 + quad * 8));
#pragma unroll
        for (int nt = 0; nt < 4; ++nt)
#pragma unroll
            for (int ks = 0; ks < 2; ++ks)
                acc[mt][nt] = __builtin_amdgcn_mfma_f32_16x16x32_f16(
                    af[ks], bfrag[nt][ks], acc[mt][nt], 0, 0, 0);
    }

    const int which = c0 >> 10;                 // 0:xl 1:xr 2:skip
    const int csec  = c0 & 1023;
    __syncthreads();
#pragma unroll
    for (int nt = 0; nt < 4; ++nt) {
        int col = csec + nw + nt * 16 + l16;
        float bias = (which == 0) ? bl1[col] : (which == 1) ? br1[col]
                                             : (bsk[col] + b1[col]);
#pragma unroll
        for (int mt = 0; mt < 4; ++mt) {
#pragma unroll
            for (int r = 0; r < 4; ++r)
                CS(mw + mt * 16 + quad * 4 + r, nw + nt * 16 + l16) =
                    (_Float16)(acc[mt][nt][r] + bias);
        }
    }
    __syncthreads();

    _Float16* __restrict__ dst = (which == 0) ? xl1h : (which == 1) ? xr1h : sk1h;
#pragma unroll
    for (int it = 0; it < 8; ++it) {
        int idx = t + 256 * it;                 // 2048 chunks of 8 halfs
        int row = idx >> 4, c16 = idx & 15;
        int grow = r0 + row;
        if (grow < n) {
            u32x4 v = *(u32x4*)(&CS(row, c16 * 8));
            *(u32x4*)(dst + (size_t)grow * F1 + csec + c16 * 8) = v;
        }
    }
}

// ------- conv1 agg + softmax + skip + LayerNorm + ELU + conv2 proj (fused)
// ONE node per 128-thread block: two waves, one feature half (q) each.
// ELL edge offsets (address = f(node) only). Per-edge readlane -> SGPR base.
// THREE 4-edge banks with guarded refills (best measured config, 68.0 us).
// conv1 is pinned at ~3.2 TB/s delivered across 6 structural variants
// (rounds 3-9) => BW-ceiling-bound on its ~209 MB of L2-miss traffic.
__global__ __launch_bounds__(128, 6) void k_conv1_ln(
    const int* __restrict__ cursor, const int* __restrict__ ell_off,
    const _Float16* __restrict__ xl1h, const _Float16* __restrict__ xr1h,
    const _Float16* __restrict__ sk1h,
    const float* __restrict__ att1,
    const float* __restrict__ g1, const float* __restrict__ beta1,
    const float* __restrict__ Wl2, const float* __restrict__ bl2,
    const float* __restrict__ Wr2, const float* __restrict__ br2,
    float* __restrict__ xl2, float* __restrict__ xr2, int n)
{
    __shared__ float sb[2][6];
    const int q    = threadIdx.x >> 6;          // wave id = feature half
    const int lane = threadIdx.x & 63;
    const int node = blockIdx.x;                // grid = n, always active
    const int cb  = q * 512 + lane * 8;
    const int cbB = cb * 2;                     // byte offset within row
    const h2 c02 = (h2){(_Float16)0.2f, (_Float16)0.2f};
    const char* __restrict__ xlB = (const char*)xl1h;

    // offset vector + degree: both depend only on node -> issue immediately
    int offv = ell_off[(node << 6) + lane];
    int deg  = cursor[node];
    deg = deg > EW ? EW : deg;                  // safety clamp (never for this graph)

    h2 xrv[4], at2[4], O[4];
    float ll = 0.f;
    float v[8];
    float s1 = 0.f, s2 = 0.f;

    {
        U4H u; u.u = *(const uint4*)(xr1h + (size_t)node * F1 + cb);
#pragma unroll
        for (int j = 0; j < 4; ++j) xrv[j] = u.h[j];
        float4 a0 = *(const float4*)(att1 + cb);
        float4 a1 = *(const float4*)(att1 + cb + 4);
        at2[0] = (h2){(_Float16)a0.x, (_Float16)a0.y};
        at2[1] = (h2){(_Float16)a0.z, (_Float16)a0.w};
        at2[2] = (h2){(_Float16)a1.x, (_Float16)a1.y};
        at2[3] = (h2){(_Float16)a1.z, (_Float16)a1.w};
#pragma unroll
        for (int j = 0; j < 4; ++j) O[j] = (h2){(_Float16)0.f, (_Float16)0.f};
    }

    auto edge = [&](const U4H& cur) {
        // two independent dot chains to break fdot2 serial dependency
        h2 s0 = cur.h[0] + xrv[0];
        h2 s1h = cur.h[1] + xrv[1];
        h2 s2h = cur.h[2] + xrv[2];
        h2 s3 = cur.h[3] + xrv[3];
        h2 r0 = __builtin_elementwise_max(s0, s0 * c02);
        h2 r1 = __builtin_elementwise_max(s1h, s1h * c02);
        h2 r2 = __builtin_elementwise_max(s2h, s2h * c02);
        h2 r3 = __builtin_elementwise_max(s3, s3 * c02);
        float pa = dot2f(r0, at2[0], 0.f);
        float pb = dot2f(r1, at2[1], 0.f);
        pa = dot2f(r2, at2[2], pa);
        pb = dot2f(r3, at2[3], pb);
        float p = red16(pa + pb);                           // per-head dot
        float w = __expf(p);                                // bounded logits
        ll += w;
        _Float16 wh = (_Float16)w;
        h2 wh2 = (h2){wh, wh};
#pragma unroll
        for (int j = 0; j < 4; ++j) O[j] = O[j] + wh2 * cur.h[j];  // v_pk_fma
    };

    // clamped load (dup-tail rows hit L1/L2)
    auto ld = [&](int k) -> U4H {
        int kk = k < deg ? k : deg - 1;
        int off = __builtin_amdgcn_readlane(offv, kk);  // uniform -> SGPR
        U4H u2; u2.u = *(const uint4*)(xlB + (unsigned)off + cbB);
        return u2;
    };
    {
        // bank prologue: A always; B/C behind uniform deg guards
        U4H A0 = ld(0), A1 = ld(1), A2 = ld(2), A3 = ld(3);
        U4H B0, B1, B2, B3, C0, C1, C2, C3;
        if (deg > 4) { B0 = ld(4); B1 = ld(5); B2 = ld(6); B3 = ld(7); }
        if (deg > 8) { C0 = ld(8); C1 = ld(9); C2 = ld(10); C3 = ld(11); }
        int i = 0;
        for (;;) {
            // consume A (edges i..i+3); banks B,C (8 gathers) in flight
            edge(A0);
            if (i + 1 < deg) edge(A1);
            if (i + 2 < deg) edge(A2);
            if (i + 3 < deg) edge(A3);
            i += 4;
            if (i >= deg) break;
            if (i + 8 < deg) { A0 = ld(i + 8); A1 = ld(i + 9);
                               A2 = ld(i + 10); A3 = ld(i + 11); }
            // consume B; banks C,A in flight
            edge(B0);
            if (i + 1 < deg) edge(B1);
            if (i + 2 < deg) edge(B2);
            if (i + 3 < deg) edge(B3);
            i += 4;
            if (i >= deg) break;
            if (i + 8 < deg) { B0 = ld(i + 8); B1 = ld(i + 9);
                               B2 = ld(i + 10); B3 = ld(i + 11); }
            // consume C; banks A,B in flight
            edge(C0);
            if (i + 1 < deg) edge(C1);
            if (i + 2 < deg) edge(C2);
            if (i + 3 < deg) edge(C3);
            i += 4;
            if (i >= deg) break;
            if (i + 8 < deg) { C0 = ld(i + 8); C1 = ld(i + 9);
                               C2 = ld(i + 10); C3 = ld(i + 11); }
        }
    }

    {
        float inv = 1.f / (ll + 1e-16f);
        U4H su; su.u = *(const uint4*)(sk1h + (size_t)node * F1 + cb);
#pragma unroll
        for (int j = 0; j < 4; ++j) {
            float xv0 = (float)su.h[j][0] + (float)O[j][0] * inv;
            float xv1 = (float)su.h[j][1] + (float)O[j][1] * inv;
            v[2 * j]     = xv0;
            v[2 * j + 1] = xv1;
            s1 += xv0 + xv1;
            s2 += xv0 * xv0 + xv1 * xv1;
        }
    }
#pragma unroll
    for (int off = 32; off > 0; off >>= 1) {
        s1 += __shfl_xor(s1, off);
        s2 += __shfl_xor(s2, off);
    }
    if (lane == 0) { sb[q][0] = s1; sb[q][1] = s2; }
    __syncthreads();
    float mu  = (sb[0][0] + sb[1][0]) * (1.f / 1024.f);
    float ms  = (sb[0][1] + sb[1][1]) * (1.f / 1024.f);
    float var = fmaxf(ms - mu * mu, 0.f);
    float inv = rsqrtf(var + 1e-5f);

    float p0 = 0.f, p1 = 0.f, p2 = 0.f, p3 = 0.f;
    {
        float4 gA = *(const float4*)(g1 + cb),    gB = *(const float4*)(g1 + cb + 4);
        float4 bA = *(const float4*)(beta1 + cb), bB = *(const float4*)(beta1 + cb + 4);
        float gv[8] = {gA.x, gA.y, gA.z, gA.w, gB.x, gB.y, gB.z, gB.w};
        float bv[8] = {bA.x, bA.y, bA.z, bA.w, bB.x, bB.y, bB.z, bB.w};
#pragma unroll
        for (int j = 0; j < 8; j += 2) {
            float4 wl = *(const float4*)(Wl2 + (cb + j) * 2);   // rows cb+j, cb+j+1
            float4 wr = *(const float4*)(Wr2 + (cb + j) * 2);
            float y0 = (v[j]   - mu) * inv * gv[j]   + bv[j];
            float y1 = (v[j+1] - mu) * inv * gv[j+1] + bv[j+1];
            float z0 = y0 > 0.f ? y0 : __expf(y0) - 1.f;       // ELU
            float z1 = y1 > 0.f ? y1 : __expf(y1) - 1.f;
            p0 += z0 * wl.x + z1 * wl.z;
            p1 += z0 * wl.y + z1 * wl.w;
            p2 += z0 * wr.x + z1 * wr.z;
            p3 += z0 * wr.y + z1 * wr.w;
        }
    }
#pragma unroll
    for (int off = 32; off > 0; off >>= 1) {
        p0 += __shfl_xor(p0, off); p1 += __shfl_xor(p1, off);
        p2 += __shfl_xor(p2, off); p3 += __shfl_xor(p3, off);
    }
    if (lane == 0) { sb[q][2] = p0; sb[q][3] = p1;
                     sb[q][4] = p2; sb[q][5] = p3; }
    __syncthreads();
    if (lane == 0 && q == 0) {
        *(float2*)(xl2 + 2 * node) =
            make_float2(sb[0][2] + sb[1][2] + bl2[0], sb[0][3] + sb[1][3] + bl2[1]);
        *(float2*)(xr2 + 2 * node) =
            make_float2(sb[0][4] + sb[1][4] + br2[0], sb[0][5] + sb[1][5] + br2[1]);
    }
}

// ------------ conv2: fused attention + softmax + agg, 1 thread/node (ELL)
__global__ __launch_bounds__(64) void k_conv2(
    const int* __restrict__ cursor, const int* __restrict__ ell_off,
    const float* __restrict__ xl2, const float* __restrict__ xr2,
    const float* __restrict__ att2, const float* __restrict__ b2,
    float* __restrict__ out2, int n)
{
    int d = blockIdx.x * blockDim.x + threadIdx.x;
    if (d >= n) return;
    float2 xr = *(const float2*)(xr2 + 2 * d);
    float a0w = att2[0], a1w = att2[1];
    float m = -INFINITY, l = 0.f, o0 = 0.f, o1 = 0.f;
    const int base = d << 6;
    int deg = cursor[d]; deg = deg > EW ? EW : deg;
    float2 pf[2];
    pf[0] = *(const float2*)(xl2 + (ell_off[base] >> 10));
    pf[1] = (1 < deg) ? *(const float2*)(xl2 + (ell_off[base + 1] >> 10)) : pf[0];
    for (int i = 0; i < deg; ++i) {
        float2 cur = pf[0];
        pf[0] = pf[1];
        if (i + 2 < deg) pf[1] = *(const float2*)(xl2 + (ell_off[base + i + 2] >> 10));
        float p = lrelu(cur.x + xr.x) * a0w + lrelu(cur.y + xr.y) * a1w;
        float nm = fmaxf(m, p);
        float sc = __expf(m - nm);
        float w  = __expf(p - nm);
        l = l * sc + w;
        o0 = o0 * sc + w * cur.x;
        o1 = o1 * sc + w * cur.y;
        m = nm;
    }
    float inv = 1.f / (l + 1e-16f);
    out2[2 * d + 0] = o0 * inv + b2[0];
    out2[2 * d + 1] = o1 * inv + b2[1];
}

// ----------------------------------------------------------------
extern "C" void kernel_launch(void* const* d_in, const int* in_sizes, int n_in,
                              void* d_out, int out_size, void* d_ws, size_t ws_size,
                              hipStream_t stream)
{
    const float* x     = (const float*)d_in[0];
    const int*   ei    = (const int*)  d_in[1];
    const float* Wl1   = (const float*)d_in[2];
    const float* bl1   = (const float*)d_in[3];
    const float* Wr1   = (const float*)d_in[4];
    const float* br1   = (const float*)d_in[5];
    const float* att1  = (const float*)d_in[6];
    const float* b1    = (const float*)d_in[7];
    const float* Wsk   = (const float*)d_in[8];
    const float* bsk   = (const float*)d_in[9];
    const float* g1    = (const float*)d_in[10];
    const float* beta1 = (const float*)d_in[11];
    const float* Wl2   = (const float*)d_in[12];
    const float* bl2   = (const float*)d_in[13];
    const float* Wr2   = (const float*)d_in[14];
    const float* br2   = (const float*)d_in[15];
    const float* att2  = (const float*)d_in[16];
    const float* b2    = (const float*)d_in[17];

    const int n  = in_sizes[0] / D;    // 20000
    const int ne = in_sizes[1] / 2;    // 160000
    const int m  = ne + n;             // incl. self loops

    float* ws = (float*)d_ws;
    size_t o = 0;
    _Float16* xl1h = (_Float16*)(ws + o); o += (size_t)n * F1 / 2;
    _Float16* xr1h = (_Float16*)(ws + o); o += (size_t)n * F1 / 2;
    _Float16* sk1h = (_Float16*)(ws + o); o += (size_t)n * F1 / 2;
    _Float16* xh   = (_Float16*)(ws + o); o += (size_t)n * D / 2;
    _Float16* WhT  = (_Float16*)(ws + o); o += (size_t)NTOT * 64 / 2;
    float* xl2    = ws + o; o += (size_t)n * 2;
    float* xr2    = ws + o; o += (size_t)n * 2;
    int* cursor   = (int*)(ws + o); o += (size_t)n;
    int* ell_off  = (int*)(ws + o); o += (size_t)n * EW;
    float* out2   = (float*)d_out;

    // --- graph structure (ELL) + f16 prep + W pack (one fused launch) ---
    (void)hipMemsetAsync(cursor, 0, (size_t)n * sizeof(int), stream);
    const int castB = ((n * D) / 4 + 255) / 256;   // 1250
    const int degB  = (m + 255) / 256;             // 704
    k_prep<<<castB + degB + NTOT / 128, 256, 0, stream>>>(
        x, xh, ei, cursor, ell_off, Wl1, Wr1, Wsk, WhT, n, ne, m, castB, degB);

    // --- MFMA GEMM (pure, packed inputs) ---
    dim3 gg((n + 127) / 128, NTOT / 128);
    k_gemm_mfma<<<gg, 256, 36864, stream>>>(xh, WhT, bl1, br1, bsk, b1,
                                            xl1h, xr1h, sk1h, n);

    // --- conv1 agg + LN + ELU + conv2 projections (1 node / 128-thr block) ---
    k_conv1_ln<<<n, 128, 0, stream>>>(cursor, ell_off, xl1h, xr1h, sk1h,
                                      att1, g1, beta1, Wl2, bl2, Wr2, br2,
                                      xl2, xr2, n);

    // --- conv2 ---
    k_conv2<<<(n + 63) / 64, 64, 0, stream>>>(cursor, ell_off, xl2, xr2, att2, b2, out2, n);
}